// Round 8
// baseline (302.322 us; speedup 1.0000x reference)
//
#include <hip/hip_runtime.h>
#include <hip/hip_bf16.h>

// GCN 2-layer, N=100000, E=1.6M, 128->128->64.
// Round 18: break the dinv serialization.
//  - deg[] computed by global fire-and-forget atomics inside k_setup's part
//    pass 1 (dinv = rsqrtf(deg+1) inline everywhere; k_bucket no longer
//    produces it).
//  - gemm128 no longer depends on bucket -> merged into k_mega2 dispatch:
//    blocks [0,196)=bucket @512thr, [196,587)=gemm128 (8 waves x 32 rows).
//    Fills bucket's 60 idle CUs with MFMA work.
//  - W-conversion blocks merged into k_setup dispatch.
//  - k_bucket register-stages the slab (20 VGPR, compile-time-indexed
//    unroll): part[] read once instead of twice.
//  - agg cores unchanged (agg_gemm at HBM-random roofline: 187MB/61.6us).

#define IN_F  128
#define HID_F 128
#define OUT_F 64

#define NPB     512    // nodes per bucket (dst>>9)
#define MAXBKT  256    // >= NBKT = ceil(N/512) = 196
#define CHUNK   4096   // edges per workgroup in part
#define SLAB    12288  // slab edges per bucket (mean ~8.2K + pad)
#define CAP     12288  // col staging capacity per bucket (LDS)
#define KREG    20     // register-staged slab entries per thread (20*512=10240)

typedef __bf16 bf16_t;
typedef __bf16 bf16x8 __attribute__((ext_vector_type(8)));
typedef float  f32x2  __attribute__((ext_vector_type(2)));
typedef float  f32x4  __attribute__((ext_vector_type(4)));
typedef unsigned u32x4 __attribute__((ext_vector_type(4)));

// ---------------- k_setup: partition (+deg atomics) || W conversion --------
// packed = (dst&511)<<17 | src  (src < 2^17 since N <= 131072)
// bcur[b*16] delta counter and deg[] zeroed by the preceding memset.
__global__ __launch_bounds__(256) void k_setup(const int* __restrict__ src,
                                               const int* __restrict__ dst, int E,
                                               int* __restrict__ bcur,
                                               unsigned* __restrict__ part,
                                               int* __restrict__ deg,
                                               const float* __restrict__ W1s,
                                               const float* __restrict__ W2s,
                                               bf16_t* __restrict__ Wdst,
                                               int n1, int n2,
                                               int NBKT, int pchunks) {
    int t = threadIdx.x;
    if ((int)blockIdx.x >= pchunks) {          // W-conversion blocks
        int i = (blockIdx.x - pchunks) * 256 + t;
        if (i < n1) Wdst[i] = (bf16_t)W1s[i];
        else if (i < n1 + n2) Wdst[i] = (bf16_t)W2s[i - n1];
        return;
    }
    __shared__ int cnt[MAXBKT];
    __shared__ int base[MAXBKT];
    __shared__ int cstart[MAXBKT];         // chunk-local exclusive start
    __shared__ unsigned stg[CHUNK];        // 16 KB payload
    __shared__ unsigned short sbk[CHUNK];  // 8 KB bucket id
    cnt[t] = 0;
    __syncthreads();
    int cbase = blockIdx.x * CHUNK;
    int cend = min(cbase + CHUNK, E);
    int clen = cend - cbase;
    for (int e = cbase + t; e < cend; e += 256) {
        int d = dst[e];
        atomicAdd(&cnt[d >> 9], 1);
        atomicAdd(&deg[d], 1);             // fire-and-forget degree count
    }
    __syncthreads();
    int c = cnt[t];
    cstart[t] = c;
    __syncthreads();
    for (int ofs = 1; ofs < 256; ofs <<= 1) {     // inclusive scan
        int add = (t >= ofs) ? cstart[t - ofs] : 0;
        __syncthreads();
        cstart[t] += add;
        __syncthreads();
    }
    int excl = cstart[t] - c;
    __syncthreads();
    cstart[t] = excl;                              // exclusive
    base[t] = (c && t < NBKT) ? (t * SLAB + atomicAdd(&bcur[t * 16], c)) : 0;
    cnt[t] = 0;
    __syncthreads();
    for (int e = cbase + t; e < cend; e += 256) {
        int d = dst[e];                            // L1/L2-hot re-read
        int b = d >> 9;
        int lp = atomicAdd(&cnt[b], 1);
        int pos = cstart[b] + lp;
        stg[pos] = (unsigned)src[e] | ((unsigned)(d & 511) << 17);
        sbk[pos] = (unsigned short)b;
    }
    __syncthreads();
    for (int i = t; i < clen; i += 256) {          // coalesced run writeout
        int b = sbk[i];
        part[base[b] + (i - cstart[b])] = stg[i];
    }
}

// ---------------- k_mega2: bucket CSR finalize || layer-1 GEMM -------------
// blocks [0,NBKT): bucket (register-staged slab, 1 node/thread, 512 thr).
// blocks [NBKT,..): gemm128 h1 = rsqrt(deg+1)*(x@W1^T), 8 waves x 32 rows.
__global__ __launch_bounds__(512) void k_mega2(const unsigned* __restrict__ part,
                                               const int* __restrict__ bcur,
                                               int2* __restrict__ off2,
                                               int* __restrict__ col,
                                               const int* __restrict__ deg,
                                               const float* __restrict__ X,
                                               const bf16_t* __restrict__ W1,
                                               bf16_t* __restrict__ H,
                                               int N, int NBKT) {
    __shared__ int lcnt[NPB];     // 2 KB
    __shared__ int lexc[NPB];     // 2 KB
    __shared__ int lcur[NPB];     // 2 KB
    __shared__ int psum[NPB];     // 2 KB
    __shared__ int stage[CAP];    // 48 KB
    int t = threadIdx.x;
    if ((int)blockIdx.x >= NBKT) {
        // ---- gemm128 role ----
        int gb = blockIdx.x - NBKT;
        int wv = t >> 6, lane = t & 63;
        int quad = lane >> 4, l16 = lane & 15;
        int row0 = gb * 256 + wv * 32;
        f32x4 acc[2][8] = {};
#pragma unroll
        for (int ks = 0; ks < 4; ks++) {
            int k0 = ks * 32 + quad * 8;
            bf16x8 a[2];
#pragma unroll
            for (int rt = 0; rt < 2; rt++) {
                int r = row0 + rt * 16 + l16;
                if (r >= N) r = N - 1;
                const float* p = X + (size_t)r * 128 + k0;
                f32x4 x0 = *(const f32x4*)p;
                f32x4 x1 = *(const f32x4*)(p + 4);
                bf16x8 tt;
                tt[0] = (bf16_t)x0[0]; tt[1] = (bf16_t)x0[1];
                tt[2] = (bf16_t)x0[2]; tt[3] = (bf16_t)x0[3];
                tt[4] = (bf16_t)x1[0]; tt[5] = (bf16_t)x1[1];
                tt[6] = (bf16_t)x1[2]; tt[7] = (bf16_t)x1[3];
                a[rt] = tt;
            }
#pragma unroll
            for (int ct = 0; ct < 8; ct++) {
                bf16x8 bfrag = *(const bf16x8*)(W1 + (size_t)(ct * 16 + l16) * 128 + k0);
#pragma unroll
                for (int rt = 0; rt < 2; rt++)
                    acc[rt][ct] = __builtin_amdgcn_mfma_f32_16x16x32_bf16(a[rt], bfrag, acc[rt][ct], 0, 0, 0);
            }
        }
#pragma unroll
        for (int rt = 0; rt < 2; rt++)
#pragma unroll
            for (int r4 = 0; r4 < 4; r4++) {
                int r = row0 + rt * 16 + quad * 4 + r4;
                if (r < N) {
                    float sc = rsqrtf((float)deg[r] + 1.0f);
#pragma unroll
                    for (int ct = 0; ct < 8; ct++)
                        H[(size_t)r * 128 + ct * 16 + l16] = (bf16_t)(sc * acc[rt][ct][r4]);
                } else if (r == N) {
#pragma unroll
                    for (int ct = 0; ct < 8; ct++)
                        H[(size_t)N * 128 + ct * 16 + l16] = (bf16_t)0.f;
                }
            }
        return;
    }
    // ---- bucket role ----
    int b = blockIdx.x;
    int node0 = b * NPB;
    int e0s = b * SLAB;
    int cnt = bcur[b * 16];       // delta counter == raw count
    lcnt[t] = 0;
    __syncthreads();
    unsigned rv[KREG];
    int nk = (cnt + 511) >> 9;
#pragma unroll
    for (int k = 0; k < KREG; k++) {
        int i = k * 512 + t;
        if (k < nk && i < cnt) {
            rv[k] = part[e0s + i];
            atomicAdd(&lcnt[rv[k] >> 17], 1);
        }
    }
    for (int i = KREG * 512 + t; i < cnt; i += 512)   // statistically unreachable
        atomicAdd(&lcnt[part[e0s + i] >> 17], 1);
    __syncthreads();
    int pc = (lcnt[t] + 7) & ~7;
    psum[t] = pc;
    __syncthreads();
    for (int ofs = 1; ofs < NPB; ofs <<= 1) {
        int add = (t >= ofs) ? psum[t - ofs] : 0;
        __syncthreads();
        psum[t] += add;
        __syncthreads();
    }
    int run = psum[t] - pc;       // exclusive padded start
    lexc[t] = run;
    lcur[t] = run;
    int node = node0 + t;
    if (node < N)
        off2[node] = make_int2(e0s + run, e0s + run + pc);
    __syncthreads();
#pragma unroll
    for (int k = 0; k < KREG; k++) {
        int i = k * 512 + t;
        if (k < nk && i < cnt) {
            unsigned p = rv[k];
            int dl = p >> 17;
            int sv = (int)(p & 0x1FFFF);
            int lp = atomicAdd(&lcur[dl], 1);
            if (lp < CAP) stage[lp] = sv;
            else col[e0s + lp] = sv;
        }
    }
    for (int i = KREG * 512 + t; i < cnt; i += 512) { // statistically unreachable
        unsigned p = part[e0s + i];
        int dl = p >> 17;
        int sv = (int)(p & 0x1FFFF);
        int lp = atomicAdd(&lcur[dl], 1);
        if (lp < CAP) stage[lp] = sv;
        else col[e0s + lp] = sv;
    }
    __syncthreads();
    {
        int en = lexc[t] + pc;
        for (int i = lcur[t]; i < en; i++) {   // <= 7 pad slots per node
            if (i < CAP) stage[i] = N; else col[e0s + i] = N;
        }
    }
    __syncthreads();
    int tot = psum[NPB - 1];
    for (int i = t; i < tot && i < CAP; i += 512) col[e0s + i] = stage[i];
}

// ---------------- gather helpers ----------------
template <int ROWE>
__device__ __forceinline__ void gather8(const bf16_t* __restrict__ hp,
                                        const int* __restrict__ col, int e,
                                        u32x4* w) {
    int4 c0 = *(const int4*)(col + e);
    int4 c1 = *(const int4*)(col + e + 4);
    w[0] = *(const u32x4*)(hp + (unsigned)c0.x * (unsigned)ROWE);
    w[1] = *(const u32x4*)(hp + (unsigned)c0.y * (unsigned)ROWE);
    w[2] = *(const u32x4*)(hp + (unsigned)c0.z * (unsigned)ROWE);
    w[3] = *(const u32x4*)(hp + (unsigned)c0.w * (unsigned)ROWE);
    w[4] = *(const u32x4*)(hp + (unsigned)c1.x * (unsigned)ROWE);
    w[5] = *(const u32x4*)(hp + (unsigned)c1.y * (unsigned)ROWE);
    w[6] = *(const u32x4*)(hp + (unsigned)c1.z * (unsigned)ROWE);
    w[7] = *(const u32x4*)(hp + (unsigned)c1.w * (unsigned)ROWE);
}

__device__ __forceinline__ void accum8(const u32x4* w, f32x2* a2) {
#pragma unroll
    for (int u = 0; u < 8; u++)
#pragma unroll
        for (int k = 0; k < 4; k++) {
            f32x2 v;
            v.x = __uint_as_float(w[u][k] << 16);
            v.y = __uint_as_float(w[u][k] & 0xffff0000u);
            a2[k] += v;                       // v_pk_add_f32
        }
}

// ---------------- fused agg128 + gemm64 (layer-1 agg + layer-2 GEMM) -------
__global__ __launch_bounds__(256) void k_agg_gemm(const bf16_t* __restrict__ h,
                                                  const int2* __restrict__ off2,
                                                  const int* __restrict__ col,
                                                  const int* __restrict__ deg,
                                                  const float* __restrict__ bias,
                                                  const bf16_t* __restrict__ W2,
                                                  bf16_t* __restrict__ h2, int N) {
    __shared__ float hl[16][132];   // +4 pad: 2-way-max bank aliasing
    __shared__ float dl[16];
    int lane = threadIdx.x & 63;
    int wv = threadIdx.x >> 6;
    int g = lane >> 4, fl = lane & 15;
    int node0 = blockIdx.x * 16;
    int node = node0 + wv * 4 + g;
    bool alive = node < N;
    int f = fl * 8;
    const bf16_t* hp = h + f;
    f32x2 a2[4] = {};
    float di = 0.f;
    if (alive) {
        u32x4 ws = *(const u32x4*)(hp + (unsigned)node * 128u);   // self row
        int2 oe = off2[node];
        di = rsqrtf((float)deg[node] + 1.0f);
#pragma unroll
        for (int k = 0; k < 4; k++) {
            f32x2 v;
            v.x = __uint_as_float(ws[k] << 16);
            v.y = __uint_as_float(ws[k] & 0xffff0000u);
            a2[k] = v;
        }
        u32x4 w[8];
        for (int e = oe.x; e < oe.y; e += 8) {
            gather8<128>(hp, col, e, w);
            accum8(w, a2);
        }
    }
    f32x4 b0 = *(const f32x4*)(bias + f);
    f32x4 b1 = *(const f32x4*)(bias + f + 4);
    int lr = wv * 4 + g;
#pragma unroll
    for (int j = 0; j < 8; j++) {
        float bv = (j < 4) ? b0[j] : b1[j - 4];
        float val = a2[j >> 1][j & 1] * di + bv;
        hl[lr][f + j] = fmaxf(val, 0.f);        // relu'd h1r row in LDS
    }
    if (fl == 0) dl[lr] = di;
    __syncthreads();

    // mini-GEMM: wave wv computes output cols [wv*16, wv*16+16)
    int quad = lane >> 4, l16 = lane & 15;
    f32x4 c4 = {0.f, 0.f, 0.f, 0.f};
#pragma unroll
    for (int ks = 0; ks < 4; ks++) {
        int k0 = ks * 32 + quad * 8;
        bf16x8 afr;
#pragma unroll
        for (int j = 0; j < 8; j++) afr[j] = (bf16_t)hl[l16][k0 + j];
        bf16x8 bfr = *(const bf16x8*)(W2 + (size_t)(wv * 16 + l16) * 128 + k0);
        c4 = __builtin_amdgcn_mfma_f32_16x16x32_bf16(afr, bfr, c4, 0, 0, 0);
    }
#pragma unroll
    for (int r4 = 0; r4 < 4; r4++) {
        int rr = quad * 4 + r4;
        int gn = node0 + rr;
        if (gn < N)
            h2[(size_t)gn * 64 + wv * 16 + l16] = (bf16_t)(dl[rr] * c4[r4]);
    }
    if (blockIdx.x == 0 && threadIdx.x < 32)    // zero sentinel row N of h2
        ((unsigned*)h2)[(size_t)N * 32 + threadIdx.x] = 0u;
}

// ---------------- agg, generic: LPN lanes/node, 64/LPN nodes/wave ---------
template <int ROWE, int LPN, bool RELU, typename TOUT>
__global__ __launch_bounds__(256) void k_agg(const bf16_t* __restrict__ h,
                                             const int2* __restrict__ off2,
                                             const int* __restrict__ col,
                                             const int* __restrict__ deg,
                                             const float* __restrict__ bias,
                                             TOUT* __restrict__ out, int N) {
    constexpr int NPW = 64 / LPN;   // nodes per wave
    int lane = threadIdx.x & 63;
    int wv = threadIdx.x >> 6;
    int g = lane / LPN, fl = lane % LPN;
    int node = blockIdx.x * (4 * NPW) + wv * NPW + g;
    if (node >= N) return;
    int f = fl * 8;
    const bf16_t* hp = h + f;
    u32x4 ws = *(const u32x4*)(hp + (unsigned)node * (unsigned)ROWE); // self row
    int2 oe = off2[node];
    float di = rsqrtf((float)deg[node] + 1.0f);
    f32x2 a2[4];
#pragma unroll
    for (int k = 0; k < 4; k++) {
        f32x2 v;
        v.x = __uint_as_float(ws[k] << 16);
        v.y = __uint_as_float(ws[k] & 0xffff0000u);
        a2[k] = v;
    }
    u32x4 w[8];
    for (int e = oe.x; e < oe.y; e += 8) {
        gather8<ROWE>(hp, col, e, w);
        accum8(w, a2);
    }
    f32x4 b0 = *(const f32x4*)(bias + f);
    f32x4 b1 = *(const f32x4*)(bias + f + 4);
    float r[8];
#pragma unroll
    for (int j = 0; j < 8; j++) {
        float bv = (j < 4) ? b0[j] : b1[j - 4];
        float val = a2[j >> 1][j & 1] * di + bv;
        if (RELU) val = fmaxf(val, 0.f);
        r[j] = val;
    }
    if constexpr (sizeof(TOUT) == 2) {
        bf16x8 v;
#pragma unroll
        for (int j = 0; j < 8; j++) v[j] = (bf16_t)r[j];
        *(bf16x8*)((bf16_t*)out + (size_t)node * ROWE + f) = v;
    } else {
        f32x4 v0 = {r[0], r[1], r[2], r[3]};
        f32x4 v1 = {r[4], r[5], r[6], r[7]};
        *(f32x4*)((float*)out + (size_t)node * ROWE + f) = v0;
        *(f32x4*)((float*)out + (size_t)node * ROWE + f + 4) = v1;
    }
}

extern "C" void kernel_launch(void* const* d_in, const int* in_sizes, int n_in,
                              void* d_out, int out_size, void* d_ws, size_t ws_size,
                              hipStream_t stream) {
    const float* x  = (const float*)d_in[0];
    const float* W1 = (const float*)d_in[1];
    const float* b1 = (const float*)d_in[2];
    const float* W2 = (const float*)d_in[3];
    const float* b2 = (const float*)d_in[4];
    const int*   ei = (const int*)d_in[5];

    int N = in_sizes[0] / IN_F;
    int E = in_sizes[5] / 2;
    const int* src = ei;
    const int* dst = ei + E;
    int NBKT = (N + NPB - 1) / NPB;           // 196
    int pchunks = (E + CHUNK - 1) / CHUNK;    // 391

    size_t woff = 0;
    auto alloc = [&](size_t bytes) {
        void* p = (char*)d_ws + woff;
        woff += (bytes + 255) & ~(size_t)255;
        return p;
    };
    int*      bcur  = (int*)alloc((size_t)NBKT * 16 * 4);   // 64B line per bucket
    int*      deg   = (int*)alloc((size_t)N * 4);            // contiguous w/ bcur
    unsigned* part  = (unsigned*)alloc((size_t)NBKT * SLAB * 4);
    int*      col   = (int*)alloc((size_t)NBKT * SLAB * 4);
    int2*     off2  = (int2*)alloc((size_t)N * 8);
    bf16_t*   Wb    = (bf16_t*)alloc((size_t)(HID_F * IN_F + OUT_F * HID_F) * 2);
    bf16_t*   W1b   = Wb;
    bf16_t*   W2b   = Wb + HID_F * IN_F;
    bf16_t*   h1    = (bf16_t*)alloc((size_t)(N + 1) * HID_F * 2);  // +1 zero row
    bf16_t*   h2b   = (bf16_t*)alloc((size_t)(N + 1) * OUT_F * 2);  // +1 zero row
    float*    outp  = (float*)d_out;

    size_t zbytes = (size_t)((char*)deg - (char*)bcur) + (size_t)N * 4;
    hipMemsetAsync(bcur, 0, zbytes, stream);

    int n1 = HID_F * IN_F, n2 = OUT_F * HID_F;
    int wconvblocks = (n1 + n2 + 255) / 256;   // 96
    k_setup<<<pchunks + wconvblocks, 256, 0, stream>>>(src, dst, E, bcur, part, deg,
                                                       W1, W2, Wb, n1, n2,
                                                       NBKT, pchunks);

    int gemmblocks = (N + 255) / 256;          // 391 (covers zero row N)
    k_mega2<<<NBKT + gemmblocks, 512, 0, stream>>>(part, bcur, off2, col, deg,
                                                   x, W1b, h1, N, NBKT);

    // fused: agg(h1)+relu -> (in LDS) @ W2^T -> dinv-scale -> h2 [bf16]
    k_agg_gemm<<<(N + 15) / 16, 256, 0, stream>>>(h1, off2, col, deg, b1, W2b, h2b, N);
    // layer 2 agg: gather h2 -> fp32 out
    k_agg<OUT_F, 8, false, float><<<(N + 31) / 32, 256, 0, stream>>>(h2b, off2, col, deg, b2, outp, N);
}

// Round 9
// 253.650 us; speedup vs baseline: 1.1919x; 1.1919x over previous
//
#include <hip/hip_runtime.h>
#include <hip/hip_bf16.h>

// GCN 2-layer, N=100000, E=1.6M, 128->128->64.
// Round 19: revert R8's global-atomic deg (measured: 1.6M far atomics = +50us,
// VALUBusy 1.25%). Back to R7 cores. New: NPB 512->256 so bucket b and gemm
// rows [256b,256b+256) coincide -> k_bucket_gemm fuses bucket CSR finalize
// with the layer-1 MFMA GEMM using block-local LDS dinv (no global dinv dep,
// no extra dispatch, no serialization link). k_part scans 512 bins via
// 2-bins-per-thread pair scan.

#define IN_F  128
#define HID_F 128
#define OUT_F 64

#define NPB     256    // nodes per bucket (dst>>8)
#define MAXBKT  512    // >= NBKT = ceil(N/256) = 391
#define CHUNK   4096   // edges per workgroup in part
#define SLAB    6144   // slab edges per bucket (mean ~4.1K raw, ~5.0K padded)
#define CAP     6144   // col staging capacity per bucket (24KB LDS)

typedef __bf16 bf16_t;
typedef __bf16 bf16x8 __attribute__((ext_vector_type(8)));
typedef float  f32x2  __attribute__((ext_vector_type(2)));
typedef float  f32x4  __attribute__((ext_vector_type(4)));
typedef unsigned u32x4 __attribute__((ext_vector_type(4)));

// ---------------- pass 0: weight conversion + bcur zero --------------------
__global__ __launch_bounds__(256) void k_pre(const float* __restrict__ W1s,
                                             const float* __restrict__ W2s,
                                             bf16_t* __restrict__ Wdst,
                                             int n1, int n2,
                                             int* __restrict__ bcur, int nb16) {
    int i = blockIdx.x * 256 + threadIdx.x;
    if (i < n1) Wdst[i] = (bf16_t)W1s[i];
    else if (i < n1 + n2) Wdst[i] = (bf16_t)W2s[i - n1];
    if (blockIdx.x == gridDim.x - 1) {
        for (int j = threadIdx.x; j < nb16; j += 256) bcur[j] = 0;
    }
}

// ---------------- pass B: partition via chunk-local counting sort ----------
// packed = (dst&255)<<17 | src  (src < 2^17 since N <= 131072)
// bcur[b*16] delta counter (zeroed by k_pre); final value = raw bucket count.
// 512 bins scanned 2-per-thread (pair scan).
__global__ __launch_bounds__(256) void k_part(const int* __restrict__ src,
                                              const int* __restrict__ dst, int E,
                                              int* __restrict__ bcur,
                                              unsigned* __restrict__ part, int NBKT) {
    __shared__ int cnt[MAXBKT];            // 2 KB
    __shared__ int base[MAXBKT];           // 2 KB
    __shared__ int cstart[MAXBKT];         // 2 KB chunk-local exclusive start
    __shared__ int psum[256];              // 1 KB
    __shared__ unsigned stg[CHUNK];        // 16 KB payload
    __shared__ unsigned short sbk[CHUNK];  // 8 KB bucket id
    int t = threadIdx.x;
    cnt[t] = 0; cnt[t + 256] = 0;
    __syncthreads();
    int cbase = blockIdx.x * CHUNK;
    int cend = min(cbase + CHUNK, E);
    int clen = cend - cbase;
    for (int e = cbase + t; e < cend; e += 256)
        atomicAdd(&cnt[dst[e] >> 8], 1);
    __syncthreads();
    int c0 = cnt[2 * t], c1 = cnt[2 * t + 1];
    psum[t] = c0 + c1;
    __syncthreads();
    for (int ofs = 1; ofs < 256; ofs <<= 1) {     // inclusive pair scan
        int add = (t >= ofs) ? psum[t - ofs] : 0;
        __syncthreads();
        psum[t] += add;
        __syncthreads();
    }
    int ex = psum[t] - (c0 + c1);
    cstart[2 * t] = ex;
    cstart[2 * t + 1] = ex + c0;
    base[2 * t] = (c0 && 2 * t < NBKT) ? (2 * t * SLAB + atomicAdd(&bcur[2 * t * 16], c0)) : 0;
    base[2 * t + 1] = (c1 && 2 * t + 1 < NBKT) ? ((2 * t + 1) * SLAB + atomicAdd(&bcur[(2 * t + 1) * 16], c1)) : 0;
    cnt[2 * t] = 0; cnt[2 * t + 1] = 0;
    __syncthreads();
    for (int e = cbase + t; e < cend; e += 256) {
        int d = dst[e];                            // L1-hot re-read
        int b = d >> 8;
        int lp = atomicAdd(&cnt[b], 1);
        int pos = cstart[b] + lp;
        stg[pos] = (unsigned)src[e] | ((unsigned)(d & 255) << 17);
        sbk[pos] = (unsigned short)b;
    }
    __syncthreads();
    for (int i = t; i < clen; i += 256) {          // coalesced run writeout
        int b = sbk[i];
        part[base[b] + (i - cstart[b])] = stg[i];
    }
}

// ---------------- pass C: bucket CSR finalize + layer-1 GEMM (fused) -------
// Block b: (1) CSR-finalize its 256 nodes (off2, col, dinv; dinv kept in LDS);
// (2) gemm128 for rows [b*256, b*256+256) scaled by the block-local dinv.
// No cross-block dependency: the gemm needs exactly the dinv this block made.
__global__ __launch_bounds__(256) void k_bucket_gemm(const unsigned* __restrict__ part,
                                                     const int* __restrict__ bcur,
                                                     int2* __restrict__ off2,
                                                     int* __restrict__ col,
                                                     float* __restrict__ dinv,
                                                     const float* __restrict__ X,
                                                     const bf16_t* __restrict__ W1,
                                                     bf16_t* __restrict__ H,
                                                     int N) {
    __shared__ int lcnt[NPB];     // 1 KB
    __shared__ int lexc[NPB];     // 1 KB
    __shared__ int lcur[NPB];     // 1 KB
    __shared__ int psum[NPB];     // 1 KB
    __shared__ float dinvl[NPB];  // 1 KB
    __shared__ int stage[CAP];    // 24 KB
    int b = blockIdx.x;
    int t = threadIdx.x;
    int node0 = b * NPB;
    int e0s = b * SLAB;
    int cnt = bcur[b * 16];       // delta counter == raw count
    lcnt[t] = 0;
    __syncthreads();
    for (int i = t; i < cnt; i += 256)
        atomicAdd(&lcnt[part[e0s + i] >> 17], 1);
    __syncthreads();
    int pc = (lcnt[t] + 7) & ~7;
    psum[t] = pc;
    __syncthreads();
    for (int ofs = 1; ofs < NPB; ofs <<= 1) {
        int add = (t >= ofs) ? psum[t - ofs] : 0;
        __syncthreads();
        psum[t] += add;
        __syncthreads();
    }
    int run = psum[t] - pc;       // exclusive padded start
    lexc[t] = run;
    lcur[t] = run;
    float di = rsqrtf((float)lcnt[t] + 1.0f);
    dinvl[t] = di;
    int node = node0 + t;
    if (node < N) {
        off2[node] = make_int2(e0s + run, e0s + run + pc);
        dinv[node] = di;
    }
    __syncthreads();
    for (int i = t; i < cnt; i += 256) {
        unsigned p = part[e0s + i];
        int dl = p >> 17;
        int sv = (int)(p & 0x1FFFF);
        int lp = atomicAdd(&lcur[dl], 1);
        if (lp < CAP) stage[lp] = sv;
        else col[e0s + lp] = sv;  // statistically unreachable (padded max ~5.9K)
    }
    __syncthreads();
    {
        int en = lexc[t] + pc;
        for (int i = lcur[t]; i < en; i++) {   // <= 7 pad slots per node
            if (i < CAP) stage[i] = N; else col[e0s + i] = N;
        }
    }
    __syncthreads();
    int tot = psum[NPB - 1];
    for (int i = t; i < tot && i < CAP; i += 256) col[e0s + i] = stage[i];

    // ---- gemm128 phase: rows [node0, node0+256), scale from LDS dinvl ----
    int wv = t >> 6, lane = t & 63;
    int quad = lane >> 4, l16 = lane & 15;
#pragma unroll
    for (int rh = 0; rh < 2; rh++) {
        int row0 = node0 + rh * 128 + wv * 32;
        f32x4 acc[2][8] = {};
#pragma unroll
        for (int ks = 0; ks < 4; ks++) {
            int k0 = ks * 32 + quad * 8;
            bf16x8 a[2];
#pragma unroll
            for (int rt = 0; rt < 2; rt++) {
                int r = row0 + rt * 16 + l16;
                if (r >= N) r = N - 1;
                const float* p = X + (size_t)r * 128 + k0;
                f32x4 x0 = *(const f32x4*)p;
                f32x4 x1 = *(const f32x4*)(p + 4);
                bf16x8 tt;
                tt[0] = (bf16_t)x0[0]; tt[1] = (bf16_t)x0[1];
                tt[2] = (bf16_t)x0[2]; tt[3] = (bf16_t)x0[3];
                tt[4] = (bf16_t)x1[0]; tt[5] = (bf16_t)x1[1];
                tt[6] = (bf16_t)x1[2]; tt[7] = (bf16_t)x1[3];
                a[rt] = tt;
            }
#pragma unroll
            for (int ct = 0; ct < 8; ct++) {
                bf16x8 bfrag = *(const bf16x8*)(W1 + (size_t)(ct * 16 + l16) * 128 + k0);
#pragma unroll
                for (int rt = 0; rt < 2; rt++)
                    acc[rt][ct] = __builtin_amdgcn_mfma_f32_16x16x32_bf16(a[rt], bfrag, acc[rt][ct], 0, 0, 0);
            }
        }
#pragma unroll
        for (int rt = 0; rt < 2; rt++)
#pragma unroll
            for (int r4 = 0; r4 < 4; r4++) {
                int r = row0 + rt * 16 + quad * 4 + r4;
                if (r < N) {
                    float sc = dinvl[r - node0];
#pragma unroll
                    for (int ct = 0; ct < 8; ct++)
                        H[(size_t)r * 128 + ct * 16 + l16] = (bf16_t)(sc * acc[rt][ct][r4]);
                } else if (r == N) {
#pragma unroll
                    for (int ct = 0; ct < 8; ct++)
                        H[(size_t)N * 128 + ct * 16 + l16] = (bf16_t)0.f;
                }
            }
    }
}

// ---------------- gather helpers ----------------
template <int ROWE>
__device__ __forceinline__ void gather8(const bf16_t* __restrict__ hp,
                                        const int* __restrict__ col, int e,
                                        u32x4* w) {
    int4 c0 = *(const int4*)(col + e);
    int4 c1 = *(const int4*)(col + e + 4);
    w[0] = *(const u32x4*)(hp + (unsigned)c0.x * (unsigned)ROWE);
    w[1] = *(const u32x4*)(hp + (unsigned)c0.y * (unsigned)ROWE);
    w[2] = *(const u32x4*)(hp + (unsigned)c0.z * (unsigned)ROWE);
    w[3] = *(const u32x4*)(hp + (unsigned)c0.w * (unsigned)ROWE);
    w[4] = *(const u32x4*)(hp + (unsigned)c1.x * (unsigned)ROWE);
    w[5] = *(const u32x4*)(hp + (unsigned)c1.y * (unsigned)ROWE);
    w[6] = *(const u32x4*)(hp + (unsigned)c1.z * (unsigned)ROWE);
    w[7] = *(const u32x4*)(hp + (unsigned)c1.w * (unsigned)ROWE);
}

__device__ __forceinline__ void accum8(const u32x4* w, f32x2* a2) {
#pragma unroll
    for (int u = 0; u < 8; u++)
#pragma unroll
        for (int k = 0; k < 4; k++) {
            f32x2 v;
            v.x = __uint_as_float(w[u][k] << 16);
            v.y = __uint_as_float(w[u][k] & 0xffff0000u);
            a2[k] += v;                       // v_pk_add_f32
        }
}

// ---------------- fused agg128 + gemm64 (layer-1 agg + layer-2 GEMM) -------
__global__ __launch_bounds__(256) void k_agg_gemm(const bf16_t* __restrict__ h,
                                                  const int2* __restrict__ off2,
                                                  const int* __restrict__ col,
                                                  const float* __restrict__ dinv,
                                                  const float* __restrict__ bias,
                                                  const bf16_t* __restrict__ W2,
                                                  bf16_t* __restrict__ h2, int N) {
    __shared__ float hl[16][132];   // +4 pad: 2-way-max bank aliasing
    __shared__ float dl[16];
    int lane = threadIdx.x & 63;
    int wv = threadIdx.x >> 6;
    int g = lane >> 4, fl = lane & 15;
    int node0 = blockIdx.x * 16;
    int node = node0 + wv * 4 + g;
    bool alive = node < N;
    int f = fl * 8;
    const bf16_t* hp = h + f;
    f32x2 a2[4] = {};
    float di = 0.f;
    if (alive) {
        u32x4 ws = *(const u32x4*)(hp + (unsigned)node * 128u);   // self row
        int2 oe = off2[node];
        di = dinv[node];
#pragma unroll
        for (int k = 0; k < 4; k++) {
            f32x2 v;
            v.x = __uint_as_float(ws[k] << 16);
            v.y = __uint_as_float(ws[k] & 0xffff0000u);
            a2[k] = v;
        }
        u32x4 w[8];
        for (int e = oe.x; e < oe.y; e += 8) {
            gather8<128>(hp, col, e, w);
            accum8(w, a2);
        }
    }
    f32x4 b0 = *(const f32x4*)(bias + f);
    f32x4 b1 = *(const f32x4*)(bias + f + 4);
    int lr = wv * 4 + g;
#pragma unroll
    for (int j = 0; j < 8; j++) {
        float bv = (j < 4) ? b0[j] : b1[j - 4];
        float val = a2[j >> 1][j & 1] * di + bv;
        hl[lr][f + j] = fmaxf(val, 0.f);        // relu'd h1r row in LDS
    }
    if (fl == 0) dl[lr] = di;
    __syncthreads();

    // mini-GEMM: wave wv computes output cols [wv*16, wv*16+16)
    int quad = lane >> 4, l16 = lane & 15;
    f32x4 c4 = {0.f, 0.f, 0.f, 0.f};
#pragma unroll
    for (int ks = 0; ks < 4; ks++) {
        int k0 = ks * 32 + quad * 8;
        bf16x8 afr;
#pragma unroll
        for (int j = 0; j < 8; j++) afr[j] = (bf16_t)hl[l16][k0 + j];
        bf16x8 bfr = *(const bf16x8*)(W2 + (size_t)(wv * 16 + l16) * 128 + k0);
        c4 = __builtin_amdgcn_mfma_f32_16x16x32_bf16(afr, bfr, c4, 0, 0, 0);
    }
#pragma unroll
    for (int r4 = 0; r4 < 4; r4++) {
        int rr = quad * 4 + r4;
        int gn = node0 + rr;
        if (gn < N)
            h2[(size_t)gn * 64 + wv * 16 + l16] = (bf16_t)(dl[rr] * c4[r4]);
    }
    if (blockIdx.x == 0 && threadIdx.x < 32)    // zero sentinel row N of h2
        ((unsigned*)h2)[(size_t)N * 32 + threadIdx.x] = 0u;
}

// ---------------- agg, generic: LPN lanes/node, 64/LPN nodes/wave ---------
template <int ROWE, int LPN, bool RELU, typename TOUT>
__global__ __launch_bounds__(256) void k_agg(const bf16_t* __restrict__ h,
                                             const int2* __restrict__ off2,
                                             const int* __restrict__ col,
                                             const float* __restrict__ dinv,
                                             const float* __restrict__ bias,
                                             TOUT* __restrict__ out, int N) {
    constexpr int NPW = 64 / LPN;   // nodes per wave
    int lane = threadIdx.x & 63;
    int wv = threadIdx.x >> 6;
    int g = lane / LPN, fl = lane % LPN;
    int node = blockIdx.x * (4 * NPW) + wv * NPW + g;
    if (node >= N) return;
    int f = fl * 8;
    const bf16_t* hp = h + f;
    u32x4 ws = *(const u32x4*)(hp + (unsigned)node * (unsigned)ROWE); // self row
    int2 oe = off2[node];
    float di = dinv[node];
    f32x2 a2[4];
#pragma unroll
    for (int k = 0; k < 4; k++) {
        f32x2 v;
        v.x = __uint_as_float(ws[k] << 16);
        v.y = __uint_as_float(ws[k] & 0xffff0000u);
        a2[k] = v;
    }
    u32x4 w[8];
    for (int e = oe.x; e < oe.y; e += 8) {
        gather8<ROWE>(hp, col, e, w);
        accum8(w, a2);
    }
    f32x4 b0 = *(const f32x4*)(bias + f);
    f32x4 b1 = *(const f32x4*)(bias + f + 4);
    float r[8];
#pragma unroll
    for (int j = 0; j < 8; j++) {
        float bv = (j < 4) ? b0[j] : b1[j - 4];
        float val = a2[j >> 1][j & 1] * di + bv;
        if (RELU) val = fmaxf(val, 0.f);
        r[j] = val;
    }
    if constexpr (sizeof(TOUT) == 2) {
        bf16x8 v;
#pragma unroll
        for (int j = 0; j < 8; j++) v[j] = (bf16_t)r[j];
        *(bf16x8*)((bf16_t*)out + (size_t)node * ROWE + f) = v;
    } else {
        f32x4 v0 = {r[0], r[1], r[2], r[3]};
        f32x4 v1 = {r[4], r[5], r[6], r[7]};
        *(f32x4*)((float*)out + (size_t)node * ROWE + f) = v0;
        *(f32x4*)((float*)out + (size_t)node * ROWE + f + 4) = v1;
    }
}

extern "C" void kernel_launch(void* const* d_in, const int* in_sizes, int n_in,
                              void* d_out, int out_size, void* d_ws, size_t ws_size,
                              hipStream_t stream) {
    const float* x  = (const float*)d_in[0];
    const float* W1 = (const float*)d_in[1];
    const float* b1 = (const float*)d_in[2];
    const float* W2 = (const float*)d_in[3];
    const float* b2 = (const float*)d_in[4];
    const int*   ei = (const int*)d_in[5];

    int N = in_sizes[0] / IN_F;
    int E = in_sizes[5] / 2;
    const int* src = ei;
    const int* dst = ei + E;
    int NBKT = (N + NPB - 1) / NPB;           // 391
    int pchunks = (E + CHUNK - 1) / CHUNK;    // 391

    size_t woff = 0;
    auto alloc = [&](size_t bytes) {
        void* p = (char*)d_ws + woff;
        woff += (bytes + 255) & ~(size_t)255;
        return p;
    };
    int*      bcur  = (int*)alloc((size_t)NBKT * 16 * 4);   // 64B line per bucket
    unsigned* part  = (unsigned*)alloc((size_t)NBKT * SLAB * 4);
    int*      col   = (int*)alloc((size_t)NBKT * SLAB * 4);
    int2*     off2  = (int2*)alloc((size_t)N * 8);
    float*    dinv  = (float*)alloc((size_t)N * 4);
    bf16_t*   Wb    = (bf16_t*)alloc((size_t)(HID_F * IN_F + OUT_F * HID_F) * 2);
    bf16_t*   W1b   = Wb;
    bf16_t*   W2b   = Wb + HID_F * IN_F;
    bf16_t*   h1    = (bf16_t*)alloc((size_t)(N + 1) * HID_F * 2);  // +1 zero row
    bf16_t*   h2b   = (bf16_t*)alloc((size_t)(N + 1) * OUT_F * 2);  // +1 zero row
    float*    outp  = (float*)d_out;

    int n1 = HID_F * IN_F, n2 = OUT_F * HID_F;
    int preblocks = (n1 + n2) / 256 + 1;      // 96 conv blocks + 1 bcur block
    k_pre<<<preblocks, 256, 0, stream>>>(W1, W2, Wb, n1, n2, bcur, NBKT * 16);
    k_part<<<pchunks, 256, 0, stream>>>(src, dst, E, bcur, part, NBKT);
    // bucket CSR finalize + layer-1 GEMM fused (block-local dinv)
    k_bucket_gemm<<<NBKT, 256, 0, stream>>>(part, bcur, off2, col, dinv,
                                            x, W1b, h1, N);
    // fused: agg(h1)+relu -> (in LDS) @ W2^T -> dinv-scale -> h2 [bf16]
    k_agg_gemm<<<(N + 15) / 16, 256, 0, stream>>>(h1, off2, col, dinv, b1, W2b, h2b, N);
    // layer 2 agg: gather h2 -> fp32 out
    k_agg<OUT_F, 8, false, float><<<(N + 31) / 32, 256, 0, stream>>>(h2b, off2, col, dinv, b2, outp, N);
}